// Round 1
// baseline (245.204 us; speedup 1.0000x reference)
//
#include <hip/hip_runtime.h>

#define BB 32
#define FF 8
#define NN 131072
#define CC 16

constexpr float DELTA_VAR  = 0.5f;
constexpr float DELTA_DIST = 1.5f;
constexpr float ALPHA = 1.0f, BETA = 1.0f, GAMMA = 0.001f;

// ws layout (floats)
#define WS_SUMS  0        // B*C*F = 4096
#define WS_CNT   4096     // B*C   = 512
#define WS_DRG   4608     // 1: beta*dist/B + gamma*reg/B
#define WS_VAR   4609     // 1: raw sum of h^2 * invcnt over all points
#define WS_MEANS 4616     // B*C*F = 4096
#define WS_INV   8712     // B*C   = 512
// zero region: floats [0, 4616)

#define CHUNKS 64
#define POINTS (NN / CHUNKS)   // 2048

// ---------------- Pass 1: per-(b,c) sums + counts ----------------
__global__ __launch_bounds__(256) void k_sums(const float* __restrict__ x,
                                              const int* __restrict__ tgt,
                                              float* __restrict__ ws) {
    __shared__ float lsum[CC * 9];   // stride-9 pad: 16 rows -> 16 distinct banks
    __shared__ float lcnt[CC];
    const int tid = threadIdx.x;
    for (int i = tid; i < CC * 9; i += 256) lsum[i] = 0.f;
    if (tid < CC) lcnt[tid] = 0.f;
    __syncthreads();

    const int b  = blockIdx.y;
    const int n0 = blockIdx.x * POINTS;
    const float* xb = x + (size_t)b * FF * NN;
    const int*   tb = tgt + (size_t)b * NN;

    for (int n = n0 + tid * 4; n < n0 + POINTS; n += 256 * 4) {
        const int4 t4 = *reinterpret_cast<const int4*>(tb + n);
        atomicAdd(&lcnt[t4.x], 1.f);
        atomicAdd(&lcnt[t4.y], 1.f);
        atomicAdd(&lcnt[t4.z], 1.f);
        atomicAdd(&lcnt[t4.w], 1.f);
#pragma unroll
        for (int f = 0; f < FF; ++f) {
            const float4 v = *reinterpret_cast<const float4*>(xb + (size_t)f * NN + n);
            atomicAdd(&lsum[t4.x * 9 + f], v.x);
            atomicAdd(&lsum[t4.y * 9 + f], v.y);
            atomicAdd(&lsum[t4.z * 9 + f], v.z);
            atomicAdd(&lsum[t4.w * 9 + f], v.w);
        }
    }
    __syncthreads();

    if (tid < CC * FF) {
        const int c = tid / FF, f = tid % FF;
        atomicAdd(&ws[WS_SUMS + (b * CC + c) * FF + f], lsum[c * 9 + f]);
    }
    if (tid >= 128 && tid < 128 + CC) {
        atomicAdd(&ws[WS_CNT + b * CC + (tid - 128)], lcnt[tid - 128]);
    }
}

// ---------------- Mid: means, invcnt, dist term, reg term ----------------
__global__ __launch_bounds__(512) void k_mid(const int* __restrict__ tgt,
                                             float* __restrict__ ws) {
    __shared__ float smeans[BB * CC * FF];  // 16 KB
    __shared__ int   st[BB * CC];           // first 16 labels per batch
    __shared__ float red[512];

    const int tid = threadIdx.x;
    const int b = tid >> 4;
    const int c = tid & 15;

    const float cnt = ws[WS_CNT + b * CC + c];
    const float inv = cnt > 0.f ? 1.f / cnt : 0.f;
    float l1 = 0.f;
#pragma unroll
    for (int f = 0; f < FF; ++f) {
        const float m = ws[WS_SUMS + (b * CC + c) * FF + f] * inv;
        smeans[(b * CC + c) * FF + f] = m;
        ws[WS_MEANS + (b * CC + c) * FF + f] = m;
        l1 += fabsf(m);
    }
    ws[WS_INV + b * CC + c] = inv;
    st[b * CC + c] = tgt[(size_t)b * NN + c];   // label of point index c (<16)

    float contrib = (GAMMA / (float)(CC * BB)) * l1;   // reg, pre-scaled
    __syncthreads();

    // dist term: mc[b][i] = means[b][ target[b][i] ], i = c here
    const int ti = st[b * CC + c];
    float mi[FF];
#pragma unroll
    for (int f = 0; f < FF; ++f) mi[f] = smeans[(b * CC + ti) * FF + f];

    float dsum = 0.f;
    for (int j = 0; j < CC; ++j) {
        const int tj = st[b * CC + j];
        float d = 0.f;
#pragma unroll
        for (int f = 0; f < FF; ++f) d += fabsf(mi[f] - smeans[(b * CC + tj) * FF + f]);
        if (j != c) {
            const float h = 2.f * DELTA_DIST - d;
            if (h > 0.f) dsum += h * h;
        }
    }
    contrib += (BETA / (float)(CC * (CC - 1) * BB)) * dsum;

    red[tid] = contrib;
    __syncthreads();
    for (int s = 256; s > 0; s >>= 1) {
        if (tid < s) red[tid] += red[tid + s];
        __syncthreads();
    }
    if (tid == 0) ws[WS_DRG] = red[0];
}

// ---------------- Pass 2: variance term ----------------
__global__ __launch_bounds__(256) void k_var(const float* __restrict__ x,
                                             const int* __restrict__ tgt,
                                             float* __restrict__ ws) {
    __shared__ float smean[CC * 9];   // stride-9 pad for conflict-light reads
    __shared__ float sinv[CC];
    const int tid = threadIdx.x;
    const int b = blockIdx.y;

    if (tid < CC * FF) {
        const int c = tid / FF, f = tid % FF;
        smean[c * 9 + f] = ws[WS_MEANS + (b * CC + c) * FF + f];
    }
    if (tid >= 128 && tid < 128 + CC) sinv[tid - 128] = ws[WS_INV + b * CC + (tid - 128)];
    __syncthreads();

    const int n0 = blockIdx.x * POINTS;
    const float* xb = x + (size_t)b * FF * NN;
    const int*   tb = tgt + (size_t)b * NN;

    float acc = 0.f;
    for (int n = n0 + tid * 4; n < n0 + POINTS; n += 256 * 4) {
        const int4 t4 = *reinterpret_cast<const int4*>(tb + n);
        float s0 = 0.f, s1 = 0.f, s2 = 0.f, s3 = 0.f;
#pragma unroll
        for (int f = 0; f < FF; ++f) {
            const float4 v = *reinterpret_cast<const float4*>(xb + (size_t)f * NN + n);
            s0 += fabsf(v.x - smean[t4.x * 9 + f]);
            s1 += fabsf(v.y - smean[t4.y * 9 + f]);
            s2 += fabsf(v.z - smean[t4.z * 9 + f]);
            s3 += fabsf(v.w - smean[t4.w * 9 + f]);
        }
        float h;
        h = fmaxf(s0 - DELTA_VAR, 0.f); acc += h * h * sinv[t4.x];
        h = fmaxf(s1 - DELTA_VAR, 0.f); acc += h * h * sinv[t4.y];
        h = fmaxf(s2 - DELTA_VAR, 0.f); acc += h * h * sinv[t4.z];
        h = fmaxf(s3 - DELTA_VAR, 0.f); acc += h * h * sinv[t4.w];
    }

    // wave -> block reduction
#pragma unroll
    for (int off = 32; off > 0; off >>= 1) acc += __shfl_down(acc, off, 64);
    __shared__ float wsum[4];
    const int wave = tid >> 6, lane = tid & 63;
    if (lane == 0) wsum[wave] = acc;
    __syncthreads();
    if (tid == 0) atomicAdd(&ws[WS_VAR], wsum[0] + wsum[1] + wsum[2] + wsum[3]);
}

// ---------------- Final combine ----------------
__global__ void k_final(const float* __restrict__ ws, float* __restrict__ out) {
    if (threadIdx.x == 0 && blockIdx.x == 0)
        out[0] = ALPHA * ws[WS_VAR] / (float)BB + ws[WS_DRG];
}

extern "C" void kernel_launch(void* const* d_in, const int* in_sizes, int n_in,
                              void* d_out, int out_size, void* d_ws, size_t ws_size,
                              hipStream_t stream) {
    const float* x  = (const float*)d_in[0];
    const int* tgt  = (const int*)d_in[1];
    float* out = (float*)d_out;
    float* ws  = (float*)d_ws;

    // zero accumulators (sums, counts, scalars) — deterministic per launch
    hipMemsetAsync(ws, 0, (size_t)4616 * sizeof(float), stream);

    dim3 grid(CHUNKS, BB);
    k_sums<<<grid, 256, 0, stream>>>(x, tgt, ws);
    k_mid<<<1, 512, 0, stream>>>(tgt, ws);
    k_var<<<grid, 256, 0, stream>>>(x, tgt, ws);
    k_final<<<1, 64, 0, stream>>>(ws, out);
}

// Round 2
// 79.227 us; speedup vs baseline: 3.0950x; 3.0950x over previous
//
#include <hip/hip_runtime.h>

#define BB 32
#define FF 8
#define NN 131072
#define CC 16

constexpr float DELTA_VAR  = 0.5f;
constexpr float DELTA_DIST = 1.5f;
constexpr float ALPHA = 1.0f, BETA = 1.0f, GAMMA = 0.001f;

// ws layout (floats)
#define WS_SUMS  0        // B*C*F = 4096
#define WS_CNT   4096     // B*C   = 512
#define WS_DRG   4608     // 1: beta*dist/B + gamma*reg/B
#define WS_VAR   4609     // 1: raw sum of h^2 * invcnt over all points
#define WS_MEANS 4616     // B*C*F = 4096
#define WS_INV   8712     // B*C   = 512
// zero region: floats [0, 4616)

#define CHUNKS 64
#define POINTS (NN / CHUNKS)   // 2048

// ---------------- Pass 1: per-(b,c) sums + counts, atomic-free ----------------
// 8 feature-groups x 32 threads. Each thread owns a private 16-slot LDS row
// (stride 17: odd stride -> consecutive tids hit distinct banks, ~2-way max).
__global__ __launch_bounds__(256) void k_sums(const float* __restrict__ x,
                                              const int* __restrict__ tgt,
                                              float* __restrict__ ws) {
    __shared__ float priv[256 * 17];   // 17.4 KB
    __shared__ float cpriv[32 * 17];   //  2.2 KB (counts, f==0 group only)
    const int tid = threadIdx.x;
#pragma unroll
    for (int i = 0; i < 16; ++i) priv[tid * 17 + i] = 0.f;
    if (tid < 32) {
#pragma unroll
        for (int i = 0; i < 16; ++i) cpriv[tid * 17 + i] = 0.f;
    }
    __syncthreads();

    const int b  = blockIdx.y;
    const int f  = tid >> 5;          // feature group 0..7
    const int g  = tid & 31;          // lane-in-group
    const int n0 = blockIdx.x * POINTS;
    const float* __restrict__ xf = x + (size_t)b * FF * NN + (size_t)f * NN;
    const int*   __restrict__ tb = tgt + (size_t)b * NN;
    const int base  = tid * 17;
    const int cbase = g * 17;

#pragma unroll 2
    for (int k = 0; k < POINTS / 128; ++k) {
        const int n = n0 + k * 128 + g * 4;
        const int4   t4 = *reinterpret_cast<const int4*>(tb + n);
        const float4 v  = *reinterpret_cast<const float4*>(xf + n);
        priv[base + t4.x] += v.x;
        priv[base + t4.y] += v.y;
        priv[base + t4.z] += v.z;
        priv[base + t4.w] += v.w;
        if (f == 0) {
            cpriv[cbase + t4.x] += 1.f;
            cpriv[cbase + t4.y] += 1.f;
            cpriv[cbase + t4.z] += 1.f;
            cpriv[cbase + t4.w] += 1.f;
        }
    }
    __syncthreads();

    // block reduce: 128 threads cover (f,c); 16 threads cover counts
    if (tid < 128) {
        const int rf = tid >> 4, rc = tid & 15;
        float s = 0.f;
#pragma unroll
        for (int gg = 0; gg < 32; ++gg) s += priv[(rf * 32 + gg) * 17 + rc];
        atomicAdd(&ws[WS_SUMS + (b * CC + rc) * FF + rf], s);
    } else if (tid < 144) {
        const int rc = tid - 128;
        float s = 0.f;
#pragma unroll
        for (int gg = 0; gg < 32; ++gg) s += cpriv[gg * 17 + rc];
        atomicAdd(&ws[WS_CNT + b * CC + rc], s);
    }
}

// ---------------- Mid: means, invcnt, dist term, reg term ----------------
__global__ __launch_bounds__(512) void k_mid(const int* __restrict__ tgt,
                                             float* __restrict__ ws) {
    __shared__ float smeans[BB * CC * FF];  // 16 KB
    __shared__ int   st[BB * CC];           // first 16 labels per batch
    __shared__ float red[512];

    const int tid = threadIdx.x;
    const int b = tid >> 4;
    const int c = tid & 15;

    const float cnt = ws[WS_CNT + b * CC + c];
    const float inv = cnt > 0.f ? 1.f / cnt : 0.f;
    float l1 = 0.f;
#pragma unroll
    for (int f = 0; f < FF; ++f) {
        const float m = ws[WS_SUMS + (b * CC + c) * FF + f] * inv;
        smeans[(b * CC + c) * FF + f] = m;
        ws[WS_MEANS + (b * CC + c) * FF + f] = m;
        l1 += fabsf(m);
    }
    ws[WS_INV + b * CC + c] = inv;
    st[b * CC + c] = tgt[(size_t)b * NN + c];   // label of point index c (<16)

    float contrib = (GAMMA / (float)(CC * BB)) * l1;   // reg, pre-scaled
    __syncthreads();

    // dist term: mc[b][i] = means[b][ target[b][i] ], i = c here
    const int ti = st[b * CC + c];
    float mi[FF];
#pragma unroll
    for (int f = 0; f < FF; ++f) mi[f] = smeans[(b * CC + ti) * FF + f];

    float dsum = 0.f;
    for (int j = 0; j < CC; ++j) {
        const int tj = st[b * CC + j];
        float d = 0.f;
#pragma unroll
        for (int f = 0; f < FF; ++f) d += fabsf(mi[f] - smeans[(b * CC + tj) * FF + f]);
        if (j != c) {
            const float h = 2.f * DELTA_DIST - d;
            if (h > 0.f) dsum += h * h;
        }
    }
    contrib += (BETA / (float)(CC * (CC - 1) * BB)) * dsum;

    red[tid] = contrib;
    __syncthreads();
    for (int s = 256; s > 0; s >>= 1) {
        if (tid < s) red[tid] += red[tid + s];
        __syncthreads();
    }
    if (tid == 0) ws[WS_DRG] = red[0];
}

// ---------------- Pass 2: variance term ----------------
__global__ __launch_bounds__(256) void k_var(const float* __restrict__ x,
                                             const int* __restrict__ tgt,
                                             float* __restrict__ ws) {
    __shared__ float smean[CC * 9];   // banks (9c+f)%32 distinct per c -> conflict-light
    __shared__ float sinv[CC];
    const int tid = threadIdx.x;
    const int b = blockIdx.y;

    if (tid < CC * FF) {
        const int c = tid / FF, f = tid % FF;
        smean[c * 9 + f] = ws[WS_MEANS + (b * CC + c) * FF + f];
    }
    if (tid >= 128 && tid < 128 + CC) sinv[tid - 128] = ws[WS_INV + b * CC + (tid - 128)];
    __syncthreads();

    const int n0 = blockIdx.x * POINTS;
    const float* xb = x + (size_t)b * FF * NN;
    const int*   tb = tgt + (size_t)b * NN;

    float acc = 0.f;
    for (int n = n0 + tid * 4; n < n0 + POINTS; n += 256 * 4) {
        const int4 t4 = *reinterpret_cast<const int4*>(tb + n);
        float s0 = 0.f, s1 = 0.f, s2 = 0.f, s3 = 0.f;
#pragma unroll
        for (int f = 0; f < FF; ++f) {
            const float4 v = *reinterpret_cast<const float4*>(xb + (size_t)f * NN + n);
            s0 += fabsf(v.x - smean[t4.x * 9 + f]);
            s1 += fabsf(v.y - smean[t4.y * 9 + f]);
            s2 += fabsf(v.z - smean[t4.z * 9 + f]);
            s3 += fabsf(v.w - smean[t4.w * 9 + f]);
        }
        float h;
        h = fmaxf(s0 - DELTA_VAR, 0.f); acc += h * h * sinv[t4.x];
        h = fmaxf(s1 - DELTA_VAR, 0.f); acc += h * h * sinv[t4.y];
        h = fmaxf(s2 - DELTA_VAR, 0.f); acc += h * h * sinv[t4.z];
        h = fmaxf(s3 - DELTA_VAR, 0.f); acc += h * h * sinv[t4.w];
    }

    // wave -> block reduction
#pragma unroll
    for (int off = 32; off > 0; off >>= 1) acc += __shfl_down(acc, off, 64);
    __shared__ float wsum[4];
    const int wave = tid >> 6, lane = tid & 63;
    if (lane == 0) wsum[wave] = acc;
    __syncthreads();
    if (tid == 0) atomicAdd(&ws[WS_VAR], wsum[0] + wsum[1] + wsum[2] + wsum[3]);
}

// ---------------- Final combine ----------------
__global__ void k_final(const float* __restrict__ ws, float* __restrict__ out) {
    if (threadIdx.x == 0 && blockIdx.x == 0)
        out[0] = ALPHA * ws[WS_VAR] / (float)BB + ws[WS_DRG];
}

extern "C" void kernel_launch(void* const* d_in, const int* in_sizes, int n_in,
                              void* d_out, int out_size, void* d_ws, size_t ws_size,
                              hipStream_t stream) {
    const float* x  = (const float*)d_in[0];
    const int* tgt  = (const int*)d_in[1];
    float* out = (float*)d_out;
    float* ws  = (float*)d_ws;

    // zero accumulators (sums, counts, scalars) — deterministic per launch
    hipMemsetAsync(ws, 0, (size_t)4616 * sizeof(float), stream);

    dim3 grid(CHUNKS, BB);
    k_sums<<<grid, 256, 0, stream>>>(x, tgt, ws);
    k_mid<<<1, 512, 0, stream>>>(tgt, ws);
    k_var<<<grid, 256, 0, stream>>>(x, tgt, ws);
    k_final<<<1, 64, 0, stream>>>(ws, out);
}